// Round 2
// baseline (3171.052 us; speedup 1.0000x reference)
//
#include <hip/hip_runtime.h>
#include <cmath>

#define A_DIM 64
#define B_DIM 256
#define K_DIM 63
#define D_DIM 66
#define FEAT 64
#define ME 256
#define VADD 196
#define KD (K_DIM * D_DIM)        // 4158
#define F_ALL (KD + VADD)         // 4354
#define PI_IN (ME + VADD)         // 452
#define H_DIM 512
#define NROWS (A_DIM * B_DIM)     // 16384
#define KT 16
#define R3 8

// ---------------------------------------------------------------------------
// Kernel 1: n[a] = sum_k features[a, k*D + (D-2)]   for a in [0,64)
// (reference's num_neighbor.reshape(-1)[:A] quirk: row index == a)
// ---------------------------------------------------------------------------
__global__ void k_counts(const float* __restrict__ feat, float* __restrict__ nbuf) {
    int a = threadIdx.x;
    if (a < A_DIM) {
        const float* row = feat + (size_t)a * F_ALL;
        float s = 0.f;
        for (int k = 0; k < K_DIM; ++k) s += row[k * D_DIM + (D_DIM - 2)];
        nbuf[a] = s;
    }
}

// ---------------------------------------------------------------------------
// Kernel 2: per row r: h1 = tanh(x @ Ws0 + bs0); h2 = tanh(h1 @ Ws1 + bs1);
// pooled[r,m] = (sum_{k < n[a]} h2[k,m]) / max(n,1)    (a = r / B)
// One block (256 threads) per row; thread m owns output channel m.
// k tiled by KT=16 so each weight load feeds 16 FMAs.
// ---------------------------------------------------------------------------
__global__ __launch_bounds__(256) void k_neigh(
    const float* __restrict__ feat,
    const float* __restrict__ Ws0, const float* __restrict__ bs0,
    const float* __restrict__ Ws1, const float* __restrict__ bs1,
    const float* __restrict__ nbuf, float* __restrict__ pooled)
{
    __shared__ float xs[64 * 64];        // 63 real k-rows + 1 zeroed pad row
    __shared__ float h1s[KT * 256];

    const int r = blockIdx.x;
    const int a = r / B_DIM;
    const int m = threadIdx.x;
    const float nf = nbuf[a];
    const int kmax = min(K_DIM, (int)nf);   // mask k<n with integer n == skip k>=n

    // stage x = me[..., :64] for this row into LDS (coalesced 64-float chunks)
    const float* row = feat + (size_t)r * F_ALL;
    for (int idx = m; idx < K_DIM * FEAT; idx += 256) {
        int k = idx >> 6, f = idx & 63;
        xs[idx] = row[k * D_DIM + f];
    }
    // zero the pad row (k=63) so layer-1 math on it is well-defined
    for (int idx = K_DIM * FEAT + m; idx < 64 * 64; idx += 256) xs[idx] = 0.f;
    __syncthreads();

    float acc = 0.f;
    const float b0 = bs0[m];
    const float b1 = bs1[m];

    for (int k0 = 0; k0 < kmax; k0 += KT) {
        // ---- layer 1: h1[k0+kk][m] = tanh(bs0[m] + sum_f x*Ws0) ----
        float h1acc[KT];
        #pragma unroll
        for (int kk = 0; kk < KT; ++kk) h1acc[kk] = b0;
        for (int f0 = 0; f0 < FEAT; f0 += 4) {
            const float w0a = Ws0[(f0 + 0) * ME + m];
            const float w0b = Ws0[(f0 + 1) * ME + m];
            const float w0c = Ws0[(f0 + 2) * ME + m];
            const float w0d = Ws0[(f0 + 3) * ME + m];
            #pragma unroll
            for (int kk = 0; kk < KT; ++kk) {
                const float4 xv = *(const float4*)&xs[(k0 + kk) * 64 + f0];
                h1acc[kk] = fmaf(xv.x, w0a, h1acc[kk]);
                h1acc[kk] = fmaf(xv.y, w0b, h1acc[kk]);
                h1acc[kk] = fmaf(xv.z, w0c, h1acc[kk]);
                h1acc[kk] = fmaf(xv.w, w0d, h1acc[kk]);
            }
        }
        #pragma unroll
        for (int kk = 0; kk < KT; ++kk) h1s[kk * 256 + m] = tanhf(h1acc[kk]);
        __syncthreads();

        // ---- layer 2: h2[kk][m] = tanh(bs1[m] + sum_j h1*Ws1) ----
        float h2acc[KT];
        #pragma unroll
        for (int kk = 0; kk < KT; ++kk) h2acc[kk] = b1;
        for (int j0 = 0; j0 < ME; j0 += 4) {
            const float w1a = Ws1[(j0 + 0) * ME + m];
            const float w1b = Ws1[(j0 + 1) * ME + m];
            const float w1c = Ws1[(j0 + 2) * ME + m];
            const float w1d = Ws1[(j0 + 3) * ME + m];
            #pragma unroll
            for (int kk = 0; kk < KT; ++kk) {
                const float4 hv = *(const float4*)&h1s[kk * 256 + j0];
                h2acc[kk] = fmaf(hv.x, w1a, h2acc[kk]);
                h2acc[kk] = fmaf(hv.y, w1b, h2acc[kk]);
                h2acc[kk] = fmaf(hv.z, w1c, h2acc[kk]);
                h2acc[kk] = fmaf(hv.w, w1d, h2acc[kk]);
            }
        }
        #pragma unroll
        for (int kk = 0; kk < KT; ++kk)
            if (k0 + kk < kmax) acc += tanhf(h2acc[kk]);
        __syncthreads();   // protect h1s before next tile overwrites it
    }

    const float invn = 1.0f / fmaxf(nf, 1.0f);
    pooled[(size_t)r * ME + m] = acc * invn;   // n==0 -> acc==0 -> 0 (matches where())
}

// ---------------------------------------------------------------------------
// Kernel 3: heads. blockIdx.y: 0=pi, 1=vf. R3=8 rows/block, 512 threads.
// pi_in = [pooled(256), self_in(196)];  out = tanh(tanh(pi_in@W0+b0)@W1+b1)
// ---------------------------------------------------------------------------
__global__ __launch_bounds__(512) void k_heads(
    const float* __restrict__ feat, const float* __restrict__ pooled,
    const float* __restrict__ W0p, const float* __restrict__ b0p,
    const float* __restrict__ W1p, const float* __restrict__ b1p,
    const float* __restrict__ W0v, const float* __restrict__ b0v,
    const float* __restrict__ W1v, const float* __restrict__ b1v,
    float* __restrict__ out)
{
    __shared__ float pin[R3][PI_IN];
    __shared__ float hb[R3][H_DIM];

    const int r0 = blockIdx.x * R3;
    const int head = blockIdx.y;
    const float* W0 = head ? W0v : W0p;
    const float* b0 = head ? b0v : b0p;
    const float* W1 = head ? W1v : W1p;
    const float* b1 = head ? b1v : b1p;
    float* o = out + (size_t)head * NROWS * H_DIM;
    const int h = threadIdx.x;

    for (int idx = h; idx < R3 * PI_IN; idx += 512) {
        int rr = idx / PI_IN, j = idx % PI_IN;
        size_t r = (size_t)(r0 + rr);
        pin[rr][j] = (j < ME) ? pooled[r * ME + j]
                              : feat[r * F_ALL + KD + (j - ME)];
    }
    __syncthreads();

    float acc[R3];
    const float bb0 = b0[h];
    #pragma unroll
    for (int rr = 0; rr < R3; ++rr) acc[rr] = bb0;
    for (int j0 = 0; j0 < PI_IN; j0 += 4) {       // 452 % 4 == 0
        const float wa = W0[(j0 + 0) * H_DIM + h];
        const float wb = W0[(j0 + 1) * H_DIM + h];
        const float wc = W0[(j0 + 2) * H_DIM + h];
        const float wd = W0[(j0 + 3) * H_DIM + h];
        #pragma unroll
        for (int rr = 0; rr < R3; ++rr) {
            const float4 pv = *(const float4*)&pin[rr][j0];
            acc[rr] = fmaf(pv.x, wa, acc[rr]);
            acc[rr] = fmaf(pv.y, wb, acc[rr]);
            acc[rr] = fmaf(pv.z, wc, acc[rr]);
            acc[rr] = fmaf(pv.w, wd, acc[rr]);
        }
    }
    #pragma unroll
    for (int rr = 0; rr < R3; ++rr) hb[rr][h] = tanhf(acc[rr]);
    __syncthreads();

    const float bb1 = b1[h];
    #pragma unroll
    for (int rr = 0; rr < R3; ++rr) acc[rr] = bb1;
    for (int j0 = 0; j0 < H_DIM; j0 += 4) {
        const float wa = W1[(j0 + 0) * H_DIM + h];
        const float wb = W1[(j0 + 1) * H_DIM + h];
        const float wc = W1[(j0 + 2) * H_DIM + h];
        const float wd = W1[(j0 + 3) * H_DIM + h];
        #pragma unroll
        for (int rr = 0; rr < R3; ++rr) {
            const float4 hv = *(const float4*)&hb[rr][j0];
            acc[rr] = fmaf(hv.x, wa, acc[rr]);
            acc[rr] = fmaf(hv.y, wb, acc[rr]);
            acc[rr] = fmaf(hv.z, wc, acc[rr]);
            acc[rr] = fmaf(hv.w, wd, acc[rr]);
        }
    }
    #pragma unroll
    for (int rr = 0; rr < R3; ++rr)
        o[(size_t)(r0 + rr) * H_DIM + h] = tanhf(acc[rr]);
}

// ---------------------------------------------------------------------------
extern "C" void kernel_launch(void* const* d_in, const int* in_sizes, int n_in,
                              void* d_out, int out_size, void* d_ws, size_t ws_size,
                              hipStream_t stream) {
    const float* feat = (const float*)d_in[0];
    const float* Ws0  = (const float*)d_in[1];
    const float* bs0  = (const float*)d_in[2];
    const float* Ws1  = (const float*)d_in[3];
    const float* bs1  = (const float*)d_in[4];
    const float* Wp0  = (const float*)d_in[5];
    const float* bp0  = (const float*)d_in[6];
    const float* Wp1  = (const float*)d_in[7];
    const float* bp1  = (const float*)d_in[8];
    const float* Wv0  = (const float*)d_in[9];
    const float* bv0  = (const float*)d_in[10];
    const float* Wv1  = (const float*)d_in[11];
    const float* bv1  = (const float*)d_in[12];
    float* out = (float*)d_out;

    float* nbuf   = (float*)d_ws;          // 64 floats (padded to 256)
    float* pooled = nbuf + 256;            // 16384*256 floats = 16.7 MB

    hipLaunchKernelGGL(k_counts, dim3(1), dim3(64), 0, stream, feat, nbuf);
    hipLaunchKernelGGL(k_neigh, dim3(NROWS), dim3(256), 0, stream,
                       feat, Ws0, bs0, Ws1, bs1, nbuf, pooled);
    hipLaunchKernelGGL(k_heads, dim3(NROWS / R3, 2), dim3(512), 0, stream,
                       feat, pooled, Wp0, bp0, Wp1, bp1, Wv0, bv0, Wv1, bv1, out);
}